// Round 11
// baseline (815.640 us; speedup 1.0000x reference)
//
#include <hip/hip_runtime.h>
#include <hip/hip_bf16.h>

// MoE E=64, top-2, T=8192, D=1024, DFF=1408. Round 11:
//  - A-operand staged via global_load_lds (width 16): per-lane global source
//    = fragment element, linear LDS dest = contiguous 1KB subtiles (no
//    swizzle, conflict-free). Removes A's reg round-trip (3 loads + 3
//    ds_writes per thread per step).
//  - Counted vmcnt: each wave waits ONLY its own 3 A-gloads (vmcnt(19))
//    before the barrier; loads span a full iteration.
//  - Everything else as r10 (whole-expert 384x64 tiles, expert->XCD pin,
//    reg-staged B with f32->bf16 convert, raw barriers).

#define S_ 2048
#define B_ 4
#define D_ 1024
#define DFF_ 1408
#define E_ 64
#define T_ 8192
#define KTOP_ 2
#define NPAIR_ (T_*KTOP_)
#define PAD_ 384
#define ROWS_ (E_*PAD_)

#define BN 64
#define BK 32

typedef __attribute__((ext_vector_type(8))) short short8;
typedef __attribute__((ext_vector_type(4))) short s16x4;
typedef __attribute__((ext_vector_type(4))) float f32x4;
typedef __attribute__((ext_vector_type(4))) unsigned short us4;

// ---------------- workspace layout (bytes) ----------------
constexpr size_t OFF_PROBS  = 0;
constexpr size_t OFF_PE     = OFF_PROBS + (size_t)T_*E_*4;
constexpr size_t OFF_PW     = OFF_PE + (size_t)NPAIR_*4;
constexpr size_t OFF_COUNTS = OFF_PW + (size_t)NPAIR_*4;
constexpr size_t OFF_CURSOR = OFF_COUNTS + 256;
constexpr size_t OFF_MESUM  = OFF_CURSOR + 256;
constexpr size_t OFF_ROWTOK = OFF_MESUM + 256;
constexpr size_t OFF_ROWW   = OFF_ROWTOK + (size_t)ROWS_*4;
constexpr size_t OFF_XBUF   = OFF_ROWW + (size_t)ROWS_*4;
constexpr size_t OFF_H      = OFF_XBUF + (size_t)ROWS_*D_*2;

__device__ __forceinline__ short f2bfs(float f) {
  union { __hip_bfloat16 h; short s; } u;
  u.h = __float2bfloat16(f);
  return u.s;
}

// async global->LDS, 16B per lane; dest = wave-uniform base + lane*16
__device__ __forceinline__ void gl_lds16(const unsigned short* g, void* l) {
  __builtin_amdgcn_global_load_lds(
      (const __attribute__((address_space(1))) unsigned int*)(g),
      (__attribute__((address_space(3))) unsigned int*)(l), 16, 0, 0);
}

// granule XOR swizzle for B staging (conflict-free writes & reads)
__device__ __forceinline__ int SWZ(int g) { return g ^ (((g >> 4) & 3) << 1); }

#define BAR() do {                                   \
    __builtin_amdgcn_sched_barrier(0);               \
    __builtin_amdgcn_s_barrier();                    \
    __builtin_amdgcn_sched_barrier(0);               \
  } while (0)
#define WAIT_LGKM0() asm volatile("s_waitcnt lgkmcnt(0)" ::: "memory")
#define VMW(N) asm volatile("s_waitcnt vmcnt(" #N ")" ::: "memory")

// ---------------- gate v2 ----------------
__device__ __forceinline__ float softmax64(float acc, int lane) {
  float m = acc;
  for (int o = 32; o; o >>= 1) m = fmaxf(m, __shfl_xor(m, o));
  float p = expf(acc - m);
  float s = p;
  for (int o = 32; o; o >>= 1) s += __shfl_xor(s, o);
  return p / s;
}

__device__ __forceinline__ void topk_write(float p, int t, int lane,
    float* __restrict__ probs, int* __restrict__ pe, float* __restrict__ pw,
    int* __restrict__ counts) {
  probs[(size_t)t * E_ + lane] = p;
  float v1 = p; int i1 = lane;
  for (int o = 32; o; o >>= 1) {
    float ov = __shfl_xor(v1, o); int oi = __shfl_xor(i1, o);
    if (ov > v1 || (ov == v1 && oi < i1)) { v1 = ov; i1 = oi; }
  }
  float v2 = (lane == i1) ? -1.f : p; int i2 = lane;
  for (int o = 32; o; o >>= 1) {
    float ov = __shfl_xor(v2, o); int oi = __shfl_xor(i2, o);
    if (ov > v2 || (ov == v2 && oi < i2)) { v2 = ov; i2 = oi; }
  }
  if (lane == 0) {
    float wsum = v1 + v2;
    pe[2 * t]     = i1; pw[2 * t]     = v1 / wsum;
    pe[2 * t + 1] = i2; pw[2 * t + 1] = v2 / wsum;
    atomicAdd(&counts[i1], 1);
    atomicAdd(&counts[i2], 1);
  }
}

__global__ __launch_bounds__(256) void gate_kernel(
    const float* __restrict__ x, const float* __restrict__ Wg,
    float* __restrict__ probs, int* __restrict__ pe, float* __restrict__ pw,
    int* __restrict__ counts) {
  int t0 = blockIdx.x * 8;
  int tid = threadIdx.x;
  int lane = tid & 63, wv = tid >> 6;
  __shared__ float tk[8][D_];
  for (int u = tid; u < 8 * (D_ / 4); u += 256) {
    int r = u >> 8, c4 = u & 255;
    int t = t0 + r;
    int b = t >> 11, s = t & (S_ - 1);
    ((float4*)tk[r])[c4] = ((const float4*)(x + (size_t)(s * B_ + b) * D_))[c4];
  }
  __syncthreads();
  const float* tkA = tk[2 * wv];
  const float* tkB = tk[2 * wv + 1];
  float acc0 = 0.f, acc1 = 0.f;
  #pragma unroll 8
  for (int d = 0; d < D_; ++d) {
    float w = Wg[(size_t)d * E_ + lane];
    acc0 += tkA[d] * w;
    acc1 += tkB[d] * w;
  }
  int ta = t0 + 2 * wv, tb = ta + 1;
  float p0 = softmax64(acc0, lane);
  float p1 = softmax64(acc1, lane);
  topk_write(p0, ta, lane, probs, pe, pw, counts);
  topk_write(p1, tb, lane, probs, pe, pw, counts);
}

// ---------------- me reduce ----------------
__global__ __launch_bounds__(256) void me_kernel(const float* __restrict__ probs,
                                                 float* __restrict__ mesum) {
  int e = blockIdx.x, tid = threadIdx.x;
  float a = 0.f;
  for (int t = tid; t < T_; t += 256) a += probs[(size_t)t * E_ + e];
  __shared__ float red[256];
  red[tid] = a; __syncthreads();
  for (int s = 128; s; s >>= 1) {
    if (tid < s) red[tid] += red[tid + s];
    __syncthreads();
  }
  if (tid == 0) mesum[e] = red[0];
}

// ---------------- finalize l_aux ----------------
__global__ __launch_bounds__(64) void finalize_kernel(
    const int* __restrict__ counts, const float* __restrict__ mesum,
    float* __restrict__ laux_out) {
  int lane = threadIdx.x;
  float contrib = (mesum[lane] / (float)T_) * ((float)counts[lane] / (float)(T_ * KTOP_));
  for (int o = 32; o; o >>= 1) contrib += __shfl_xor(contrib, o);
  if (lane == 0) laux_out[0] = (float)E_ * contrib;
}

// ---------------- scatter ----------------
__global__ __launch_bounds__(64) void scatter_kernel(
    const float* __restrict__ x, const int* __restrict__ pe, const float* __restrict__ pw,
    int* __restrict__ cursor, int* __restrict__ rowtok, float* __restrict__ roww,
    unsigned short* __restrict__ xbuf) {
  int p = blockIdx.x;
  int lane = threadIdx.x;
  __shared__ int srow;
  if (lane == 0) {
    int e = pe[p];
    int slot = atomicAdd(&cursor[e], 1);
    int row = (slot < PAD_) ? (e * PAD_ + slot) : -1;
    if (row >= 0) { rowtok[row] = p >> 1; roww[row] = pw[p]; }
    srow = row;
  }
  __syncthreads();
  int row = srow;
  if (row < 0) return;
  int t = p >> 1;
  int b = t >> 11, s = t & (S_ - 1);
  const float4* src = (const float4*)(x + (size_t)(s * B_ + b) * D_);
  unsigned short* dst = xbuf + (size_t)row * D_;
  for (int i = lane; i < D_ / 4; i += 64) {
    float4 v = src[i];
    us4 o;
    o.x = (unsigned short)f2bfs(v.x); o.y = (unsigned short)f2bfs(v.y);
    o.z = (unsigned short)f2bfs(v.z); o.w = (unsigned short)f2bfs(v.w);
    *(us4*)(dst + i * 4) = o;
  }
}

// ---------------- ffn1: whole-expert 384x64, A via global_load_lds ----------------
__global__ __launch_bounds__(512, 2) void ffn1_kernel(
    const unsigned short* __restrict__ xbuf, const float* __restrict__ W1,
    const float* __restrict__ W3, const int* __restrict__ counts,
    unsigned short* __restrict__ h) {
  // grid 1408 = (8 e-groups x 22 ni) x 8 xcd; expert e pinned to XCD e%8
  int bid = blockIdx.x;
  int r = bid & 7, u = bid >> 3;
  int ni = u % 22;
  int e = (u / 22) * 8 + r;
  int n0 = ni * BN;
  int Me = min(counts[e], PAD_);

  const unsigned short* A = xbuf + (size_t)e * PAD_ * D_;
  const float* B1p = W1 + (size_t)e * D_ * DFF_ + n0;
  const float* B3p = W3 + (size_t)e * D_ * DFF_ + n0;
  unsigned short* hptr = h + (size_t)e * PAD_ * DFF_;

  __shared__ short Als[2 * PAD_ * BK];   // 2 x 24KB, 24 linear 1KB subtiles each
  __shared__ short B1s[2 * BK * BN];     // 2 x 4KB
  __shared__ short B3s[2 * BK * BN];     // 2 x 4KB

  int tid = threadIdx.x;
  int lane = tid & 63;
  int wv = tid >> 6, wr = wv >> 1, wc = wv & 1;

  // B staging: waves 0..3 -> B1 (bks=wv), waves 4..7 -> B3
  int bks = wv & 3, bc = lane;
  int boff = ((bc >> 4) << 10) + (SWZ((bks << 4) + (bc & 15)) << 4);
  const float* qB = ((wv < 4) ? B1p : B3p) + (size_t)(bks * 8) * DFF_ + bc;
  char* Bdst = (char*)((wv < 4) ? B1s : B3s);

  // A gload: wave wv owns subtiles wv*3+{0,1,2}; per-lane source = frag elem:
  // row = wv*48 + s*16 + (lane&15), k-octet = lane>>4
  const unsigned short* qaG0 = A + (size_t)(wv * 48 + (lane & 15)) * D_ + ((lane >> 4) << 3);
  const unsigned short* qaG1 = qaG0 + BK;   // odd tiles

  float fBE[8], fBO[8];
  f32x4 acc1[6][2] = {};
  f32x4 acc3[6][2] = {};

#define F1_BLOAD(SET) do {                                               \
    _Pragma("unroll")                                                    \
    for (int j = 0; j < 8; ++j) fB##SET[j] = qB[(size_t)j * DFF_];       \
    qB += (size_t)BK * DFF_;                                             \
  } while (0)

#define F1_BWRITE(SET, BUF) do {                                         \
    short8 sb;                                                           \
    _Pragma("unroll")                                                    \
    for (int j = 0; j < 8; ++j) sb[j] = f2bfs(fB##SET[j]);               \
    *(short8*)(Bdst + (BUF)*4096 + boff) = sb;                           \
  } while (0)

#define F1_AGLOAD(BUF, Q) do {                                           \
    gl_lds16(Q,                     (char*)Als + (BUF)*24576 + ((wv*3+0) << 10)); \
    gl_lds16(Q + (size_t)16 * D_,   (char*)Als + (BUF)*24576 + ((wv*3+1) << 10)); \
    gl_lds16(Q + (size_t)32 * D_,   (char*)Als + (BUF)*24576 + ((wv*3+2) << 10)); \
    Q += 2 * BK;                                                         \
  } while (0)

#define F1_MFMA(BUF) do {                                                \
    int lsw = SWZ(lane) << 4;                                            \
    short8 af[6];                                                        \
    _Pragma("unroll")                                                    \
    for (int mi = 0; mi < 6; ++mi)                                       \
      af[mi] = *(const short8*)((char*)Als + (BUF)*24576 + ((wr * 6 + mi) << 10) + (lane << 4)); \
    __builtin_amdgcn_s_setprio(1);                                       \
    _Pragma("unroll")                                                    \
    for (int q = 0; q < 2; ++q) {                                        \
      short8 bf1 = *(const short8*)((char*)B1s + (BUF)*4096 + (((wc << 1) + q) << 10) + lsw); \
      short8 bf3 = *(const short8*)((char*)B3s + (BUF)*4096 + (((wc << 1) + q) << 10) + lsw); \
      _Pragma("unroll")                                                  \
      for (int mi = 0; mi < 6; ++mi) {                                   \
        acc1[mi][q] = __builtin_amdgcn_mfma_f32_16x16x32_bf16(af[mi], bf1, acc1[mi][q], 0, 0, 0); \
        acc3[mi][q] = __builtin_amdgcn_mfma_f32_16x16x32_bf16(af[mi], bf3, acc3[mi][q], 0, 0, 0); \
      }                                                                  \
    }                                                                    \
    __builtin_amdgcn_s_setprio(0);                                       \
  } while (0)

  // 32 K-tiles. Issue order per tile: B(8) then A-gload(3).
  // Steady invariant: 22 outstanding vmem ops/thread; vmcnt(19) drains
  // exactly this wave's A-set for the buffer about to be consumed.
  F1_BLOAD(E);            // B t0 (8)
  F1_AGLOAD(0, qaG0);     // A t0 (3)
  F1_BLOAD(O);            // B t1 (8)
  F1_AGLOAD(1, qaG1);     // A t1 (3)
  for (int it = 0; it < 15; ++it) {
    F1_BWRITE(E, 0);      // compiler drains B_E regs (vmcnt(14))
    F1_BLOAD(E);          // B t(2it+2)
    WAIT_LGKM0(); VMW(19);  // own A(buf0) done
    BAR();
    F1_MFMA(0);
    BAR();
    F1_AGLOAD(0, qaG0);   // A t(2it+2) -> buf0 (safe: all waves past MFMA(0))
    F1_BWRITE(O, 1);
    F1_BLOAD(O);          // B t(2it+3)
    WAIT_LGKM0(); VMW(19);
    BAR();
    F1_MFMA(1);
    BAR();
    F1_AGLOAD(1, qaG1);   // A t(2it+3) -> buf1
  }
  // epilogue: tiles 30 (buf0), 31 (buf1); no further loads
  F1_BWRITE(E, 0); WAIT_LGKM0(); VMW(11); BAR();
  F1_MFMA(0); BAR();
  F1_BWRITE(O, 1); WAIT_LGKM0(); VMW(0); BAR();
  F1_MFMA(1);

  // epilogue: silu(acc1)*acc3 -> bf16 h ; C: col=lane&15, row=(lane>>4)*4+j
  int lr = (lane >> 4) << 2, lc = lane & 15;
  #pragma unroll
  for (int mi = 0; mi < 6; ++mi) {
    #pragma unroll
    for (int j = 0; j < 4; ++j) {
      int m = wr * 96 + mi * 16 + lr + j;
      if (m < Me) {
        unsigned short* hp = hptr + (size_t)m * DFF_ + n0 + (wc << 5) + lc;
        #pragma unroll
        for (int q = 0; q < 2; ++q) {
          float a = acc1[mi][q][j];
          float gt = a / (1.f + __expf(-a));
          hp[q << 4] = (unsigned short)f2bfs(gt * acc3[mi][q][j]);
        }
      }
    }
  }
}

// ---------------- ffn2: whole-expert 384x64, A via global_load_lds ----------------
__global__ __launch_bounds__(512, 2) void ffn2_kernel(
    const unsigned short* __restrict__ h, const float* __restrict__ W2,
    const int* __restrict__ counts, const int* __restrict__ rowtok,
    const float* __restrict__ roww, float* __restrict__ y) {
  // grid 1024 = (8 e-groups x 16 ni) x 8 xcd
  int bid = blockIdx.x;
  int r = bid & 7, u = bid >> 3;
  int ni = u % 16;
  int e = (u / 16) * 8 + r;
  int n0 = ni * BN;
  int Me = min(counts[e], PAD_);

  const unsigned short* A = h + (size_t)e * PAD_ * DFF_;
  const float* Bw = W2 + (size_t)e * DFF_ * D_ + n0;

  __shared__ short Als[2 * PAD_ * BK];   // 2 x 24KB
  __shared__ short Bs[2 * BK * BN];      // 2 x 4KB

  int tid = threadIdx.x;
  int lane = tid & 63;
  int wv = tid >> 6, wr = wv >> 1, wc = wv & 1;

  // B staging: wave wv loads k rows wv*4..wv*4+3, lane = col (4 f32/thread);
  // writes the (wv&1) 8-byte half of granule (kseg=wv>>1, col).
  int bks2 = wv >> 1, bc = lane;
  int boff = ((bc >> 4) << 10) + (SWZ((bks2 << 4) + (bc & 15)) << 4) + ((wv & 1) << 3);
  const float* qB = Bw + (size_t)(wv * 4) * D_ + bc;

  const unsigned short* qaG0 = A + (size_t)(wv * 48 + (lane & 15)) * DFF_ + ((lane >> 4) << 3);
  const unsigned short* qaG1 = qaG0 + BK;

  float fBE[4], fBO[4];
  f32x4 acc[6][2] = {};

#define F2_BLOAD(SET) do {                                               \
    _Pragma("unroll")                                                    \
    for (int j = 0; j < 4; ++j) fB##SET[j] = qB[(size_t)j * D_];         \
    qB += (size_t)BK * D_;                                               \
  } while (0)

#define F2_BWRITE(SET, BUF) do {                                         \
    s16x4 sb;                                                            \
    _Pragma("unroll")                                                    \
    for (int j = 0; j < 4; ++j) sb[j] = f2bfs(fB##SET[j]);               \
    *(s16x4*)((char*)Bs + (BUF)*4096 + boff) = sb;                       \
  } while (0)

#define F2_AGLOAD(BUF, Q) do {                                           \
    gl_lds16(Q,                      (char*)Als + (BUF)*24576 + ((wv*3+0) << 10)); \
    gl_lds16(Q + (size_t)16 * DFF_,  (char*)Als + (BUF)*24576 + ((wv*3+1) << 10)); \
    gl_lds16(Q + (size_t)32 * DFF_,  (char*)Als + (BUF)*24576 + ((wv*3+2) << 10)); \
    Q += 2 * BK;                                                         \
  } while (0)

#define F2_MFMA(BUF) do {                                                \
    int lsw = SWZ(lane) << 4;                                            \
    short8 af[6];                                                        \
    _Pragma("unroll")                                                    \
    for (int mi = 0; mi < 6; ++mi)                                       \
      af[mi] = *(const short8*)((char*)Als + (BUF)*24576 + ((wr * 6 + mi) << 10) + (lane << 4)); \
    __builtin_amdgcn_s_setprio(1);                                       \
    _Pragma("unroll")                                                    \
    for (int q = 0; q < 2; ++q) {                                        \
      short8 bfr = *(const short8*)((char*)Bs + (BUF)*4096 + (((wc << 1) + q) << 10) + lsw); \
      _Pragma("unroll")                                                  \
      for (int mi = 0; mi < 6; ++mi)                                     \
        acc[mi][q] = __builtin_amdgcn_mfma_f32_16x16x32_bf16(af[mi], bfr, acc[mi][q], 0, 0, 0); \
    }                                                                    \
    __builtin_amdgcn_s_setprio(0);                                       \
  } while (0)

  // 44 K-tiles. Per-tile issues: B(4) then A(3) -> steady 14 outstanding;
  // vmcnt(11) drains own A-set for the buffer about to be consumed.
  F2_BLOAD(E);
  F2_AGLOAD(0, qaG0);
  F2_BLOAD(O);
  F2_AGLOAD(1, qaG1);
  for (int it = 0; it < 21; ++it) {
    F2_BWRITE(E, 0);
    F2_BLOAD(E);
    WAIT_LGKM0(); VMW(11);
    BAR();
    F2_MFMA(0);
    BAR();
    F2_AGLOAD(0, qaG0);
    F2_BWRITE(O, 1);
    F2_BLOAD(O);
    WAIT_LGKM0(); VMW(11);
    BAR();
    F2_MFMA(1);
    BAR();
    F2_AGLOAD(1, qaG1);
  }
  // epilogue: tiles 42 (buf0), 43 (buf1)
  F2_BWRITE(E, 0); WAIT_LGKM0(); VMW(7); BAR();
  F2_MFMA(0); BAR();
  F2_BWRITE(O, 1); WAIT_LGKM0(); VMW(0); BAR();
  F2_MFMA(1);

  int lr = (lane >> 4) << 2, lc = lane & 15;
  #pragma unroll
  for (int mi = 0; mi < 6; ++mi) {
    #pragma unroll
    for (int j = 0; j < 4; ++j) {
      int m = wr * 96 + mi * 16 + lr + j;
      if (m < Me) {
        int rw = e * PAD_ + m;
        int t = rowtok[rw];
        float w = roww[rw];
        int b = t >> 11, s = t & (S_ - 1);
        float* yp = y + (size_t)(s * B_ + b) * D_ + n0 + (wc << 5) + lc;
        #pragma unroll
        for (int q = 0; q < 2; ++q)
          atomicAdd(&yp[q << 4], w * acc[mi][q][j]);   // exactly 2 adds/elem
      }
    }
  }
}

extern "C" void kernel_launch(void* const* d_in, const int* in_sizes, int n_in,
                              void* d_out, int out_size, void* d_ws, size_t ws_size,
                              hipStream_t stream) {
  const float* x  = (const float*)d_in[0];
  const float* Wg = (const float*)d_in[1];
  const float* W1 = (const float*)d_in[2];
  const float* W3 = (const float*)d_in[3];
  const float* W2 = (const float*)d_in[4];
  float* y = (float*)d_out;
  float* laux = y + (size_t)S_ * B_ * D_;

  char* ws = (char*)d_ws;
  float* probs  = (float*)(ws + OFF_PROBS);
  int*   pe     = (int*)  (ws + OFF_PE);
  float* pw     = (float*)(ws + OFF_PW);
  int*   counts = (int*)  (ws + OFF_COUNTS);
  int*   cursor = (int*)  (ws + OFF_CURSOR);
  float* mesum  = (float*)(ws + OFF_MESUM);
  int*   rowtok = (int*)  (ws + OFF_ROWTOK);
  float* roww   = (float*)(ws + OFF_ROWW);
  unsigned short* xbuf = (unsigned short*)(ws + OFF_XBUF);
  unsigned short* h    = (unsigned short*)(ws + OFF_H);

  hipMemsetAsync(d_out, 0, (size_t)out_size * sizeof(float), stream);
  hipMemsetAsync(counts, 0, 512, stream);  // counts + cursor

  gate_kernel<<<T_ / 8, 256, 0, stream>>>(x, Wg, probs, pe, pw, counts);
  me_kernel<<<E_, 256, 0, stream>>>(probs, mesum);
  finalize_kernel<<<1, 64, 0, stream>>>(counts, mesum, laux);
  scatter_kernel<<<NPAIR_, 64, 0, stream>>>(x, pe, pw, cursor, rowtok, roww, xbuf);
  ffn1_kernel<<<(E_ / 8) * 22 * 8, 512, 0, stream>>>(xbuf, W1, W3, counts, h);
  ffn2_kernel<<<(E_ / 8) * 16 * 8, 512, 0, stream>>>(h, W2, counts, rowtok, roww, y);
}